// Round 8
// baseline (182.222 us; speedup 1.0000x reference)
//
#include <hip/hip_runtime.h>
#include <hip/hip_bf16.h>
#include <hip/hip_fp16.h>

#define N_NODES 100000
#define D 64
#define N_EDGES 1250000

// fine buckets (sortgather granularity)
#define RB 64                   // nodes per fine bucket (dst>>6)
#define NB 1563                 // ceil(N / 64)
#define FCAP 1536               // fine slab capacity; mean 800, max ~950
#define SORT_CAP 1536

// coarse buckets (partition pass A)
#define CB_SHIFT 11             // 2048 nodes per coarse bucket
#define NCB 49                  // ceil(N / 2048)
#define CCAP 28672              // mean 25510, sigma ~158 -> +20 sigma
#define FINE_PER_COARSE 32      // 2048/64

#define EPB 8192                // edges per pass-A block
#define PARTA_BLOCKS ((N_EDGES + EPB - 1) / EPB)   // 153
#define SEGS 8                  // pass-B blocks per coarse bucket

typedef unsigned short ushort_t;

__device__ __forceinline__ ushort_t f2h(float f) {
    return __half_as_ushort(__float2half_rn(f));
}

// ---------------------------------------------------------------------------
// Pre-transform: y = fp16(x @ W_l) to ws; z = x @ W_r + b_l (fp32) into d_out
// (sortgather reads z back and overwrites with tanh(acc+z); each out element
// is owned by exactly one bucket block -> no race).
// Block 0 zeroes both cursor arrays (replaces memset dispatches).
// ---------------------------------------------------------------------------
#define TN 64
#define FS 68   // 64 + 4 pad

__global__ __launch_bounds__(256) void pre_kernel(
    const float* __restrict__ x, const float* __restrict__ W_l,
    const float* __restrict__ b_l, const float* __restrict__ W_r,
    ushort_t* __restrict__ y, float* __restrict__ zout,
    int* __restrict__ ccursor, int* __restrict__ fcursor, int N)
{
    __shared__ float sW[2 * 64 * 64];   // [0..4095]=W_l, [4096..8191]=W_r
    __shared__ float sX[TN * FS];

    int t = threadIdx.x;
    if (blockIdx.x == 0) {
        for (int i = t; i < NCB; i += 256) ccursor[i] = 0;
        for (int i = t; i < NB; i += 256) fcursor[i] = 0;
    }
    for (int i = t; i < 64 * 64; i += 256) {
        sW[i] = W_l[i];
        sW[4096 + i] = W_r[i];
    }

    long base = (long)blockIdx.x * TN;
    for (int i = t; i < TN * 16; i += 256) {   // 64 nodes x 16 float4
        int n = i >> 4, q = i & 15;
        long node = base + n;
        float4 v = make_float4(0.f, 0.f, 0.f, 0.f);
        if (node < N) v = ((const float4*)(x + node * D))[q];
        *(float4*)&sX[n * FS + q * 4] = v;
    }
    __syncthreads();

    const int og = (t & 15) * 4;
    const int ng = (t >> 4) * 4;
    float4 b = *(const float4*)(b_l + og);

    float accL[4][4], accR[4][4];
#pragma unroll
    for (int i = 0; i < 4; i++) {
        accL[i][0] = 0.f; accL[i][1] = 0.f; accL[i][2] = 0.f; accL[i][3] = 0.f;
        accR[i][0] = b.x; accR[i][1] = b.y; accR[i][2] = b.z; accR[i][3] = b.w;
    }

#pragma unroll 2
    for (int k = 0; k < 64; k += 4) {
        float4 wl[4], wr[4], a[4];
#pragma unroll
        for (int j = 0; j < 4; j++) {
            wl[j] = *(const float4*)&sW[(k + j) * 64 + og];
            wr[j] = *(const float4*)&sW[4096 + (k + j) * 64 + og];
        }
#pragma unroll
        for (int i = 0; i < 4; i++) a[i] = *(const float4*)&sX[(ng + i) * FS + k];
#pragma unroll
        for (int i = 0; i < 4; i++) {
            float av[4] = {a[i].x, a[i].y, a[i].z, a[i].w};
#pragma unroll
            for (int j = 0; j < 4; j++) {
                accL[i][0] += av[j] * wl[j].x;
                accL[i][1] += av[j] * wl[j].y;
                accL[i][2] += av[j] * wl[j].z;
                accL[i][3] += av[j] * wl[j].w;
                accR[i][0] += av[j] * wr[j].x;
                accR[i][1] += av[j] * wr[j].y;
                accR[i][2] += av[j] * wr[j].z;
                accR[i][3] += av[j] * wr[j].w;
            }
        }
    }

#pragma unroll
    for (int i = 0; i < 4; i++) {
        long node = base + ng + i;
        if (node < N) {
            ushort4 py;
            py.x = f2h(accL[i][0]); py.y = f2h(accL[i][1]);
            py.z = f2h(accL[i][2]); py.w = f2h(accL[i][3]);
            *(ushort4*)(y + node * D + og) = py;
            float4 pz = make_float4(accR[i][0], accR[i][1], accR[i][2], accR[i][3]);
            *(float4*)(zout + node * D + og) = pz;
        }
    }
}

// ---------------------------------------------------------------------------
// Partition pass A: 49 coarse buckets (dst>>11). Runs of ~167 entries per
// (block,bucket) -> near-perfect write coalescing (round-7 lesson: run
// length = EPB/NBUCKETS governs partition write amplification).
// Packs src | coarseLocal<<17 (28 bits).
// ---------------------------------------------------------------------------
__global__ __launch_bounds__(256) void partA_kernel(
    const int* __restrict__ src, const int* __restrict__ dst,
    int* __restrict__ ccursor, unsigned* __restrict__ coarse, int E)
{
    __shared__ int hist[NCB];
    __shared__ int bbase[NCB];
    int t = threadIdx.x;
    if (t < NCB) hist[t] = 0;
    __syncthreads();

    int base = blockIdx.x * EPB;
    int lim = E - base; if (lim > EPB) lim = EPB;

    for (int i = t; i < lim; i += 256) {
        int d = dst[base + i];
        atomicAdd(&hist[d >> CB_SHIFT], 1);
    }
    __syncthreads();

    if (t < NCB) {
        int c = hist[t];
        bbase[t] = c ? atomicAdd(&ccursor[t], c) : 0;
    }
    __syncthreads();

    for (int i = t; i < lim; i += 256) {
        int d = dst[base + i];
        int s = src[base + i];
        int b = d >> CB_SHIFT;
        int pos = atomicSub(&hist[b], 1) - 1;
        coarse[(size_t)b * CCAP + bbase[b] + pos] =
            (unsigned)s | ((unsigned)(d & ((1 << CB_SHIFT) - 1)) << 17);
    }
}

// ---------------------------------------------------------------------------
// Partition pass B: 8 segment-blocks per coarse bucket (392 blocks). Each
// scatters its ~3.2K entries into the 32 fine buckets inside the coarse
// bucket (runs ~100 entries -> coalesced). Repacks src | fineLocal<<17.
// ---------------------------------------------------------------------------
__global__ __launch_bounds__(256) void partB_kernel(
    const unsigned* __restrict__ coarse, const int* __restrict__ ccursor,
    int* __restrict__ fcursor, unsigned* __restrict__ fine)
{
    __shared__ int hist[FINE_PER_COARSE];
    __shared__ int bbase[FINE_PER_COARSE];
    int cb = blockIdx.x >> 3;
    int seg = blockIdx.x & 7;
    int t = threadIdx.x;

    int cnt = ccursor[cb];
    int segLen = (cnt + SEGS - 1) / SEGS;
    int beg = seg * segLen;
    int end = beg + segLen; if (end > cnt) end = cnt;

    if (t < FINE_PER_COARSE) hist[t] = 0;
    __syncthreads();

    const unsigned* __restrict__ slab = coarse + (size_t)cb * CCAP;

    for (int i = beg + t; i < end; i += 256) {
        unsigned e = slab[i];
        atomicAdd(&hist[(e >> 17) >> 6], 1);
    }
    __syncthreads();

    if (t < FINE_PER_COARSE) {
        int c = hist[t];
        int fb = cb * FINE_PER_COARSE + t;   // global fine bucket
        bbase[t] = c ? atomicAdd(&fcursor[fb], c) : 0;
    }
    __syncthreads();

    for (int i = beg + t; i < end; i += 256) {
        unsigned e = slab[i];
        unsigned cl = e >> 17;               // coarse-local dst (11 bits)
        int fb_loc = cl >> 6;
        int pos = atomicSub(&hist[fb_loc], 1) - 1;
        size_t fb = (size_t)cb * FINE_PER_COARSE + fb_loc;
        fine[fb * FCAP + bbase[fb_loc] + pos] =
            (e & 0x1FFFFu) | ((cl & 63u) << 17);
    }
}

// ---------------------------------------------------------------------------
// Fused sort + gather (unchanged from round 7): one block per fine bucket.
// Counting sort in LDS (int atomics only), then quarter-wave gather:
// 16 lanes x 8 B = one wave-instruction moves 4 fp16 rows.
// Epilogue: out = tanh(acc + z), z staged in out by pre_kernel.
// ---------------------------------------------------------------------------
__global__ __launch_bounds__(256) void sortgather_kernel(
    const ushort_t* __restrict__ y, const unsigned* __restrict__ part,
    const int* __restrict__ cursor, float* __restrict__ out, int N)
{
    __shared__ unsigned ent[SORT_CAP];
    __shared__ int sorted[SORT_CAP];
    __shared__ int hist[RB];
    __shared__ int scanv[RB];
    __shared__ int cur[RB];
    __shared__ int begL[RB];

    int b = blockIdx.x;
    int t = threadIdx.x;
    int cnt = cursor[b];
    if (cnt > SORT_CAP) cnt = SORT_CAP;   // unreachable (max ~950)
    const unsigned* __restrict__ slab = part + (size_t)b * FCAP;

    if (t < RB) hist[t] = 0;
    for (int i = t; i < cnt; i += 256) ent[i] = slab[i];
    __syncthreads();

    for (int i = t; i < cnt; i += 256) atomicAdd(&hist[ent[i] >> 17], 1);
    __syncthreads();

    if (t < RB) scanv[t] = hist[t];
    __syncthreads();
#pragma unroll
    for (int off = 1; off < RB; off <<= 1) {
        int v = 0;
        if (t < RB && t >= off) v = scanv[t - off];
        __syncthreads();
        if (t < RB) scanv[t] += v;
        __syncthreads();
    }
    if (t < RB) {
        int ex = scanv[t] - hist[t];      // exclusive prefix
        cur[t] = ex;
        begL[t] = ex;
    }
    __syncthreads();

    for (int i = t; i < cnt; i += 256) {
        unsigned e = ent[i];
        int pos = atomicAdd(&cur[e >> 17], 1);
        sorted[pos] = (int)(e & 0x1FFFF);
    }
    __syncthreads();

    // ---- gather phase ----
    const int q  = t & 15;    // feature quad: features 4q..4q+3
    const int qw = t >> 4;    // quarter-wave id 0..15

#pragma unroll
    for (int k = 0; k < 4; k++) {
        int n = qw + 16 * k;              // local node
        int myBeg = begL[n];
        int myDeg = hist[n];
        float4 acc = make_float4(0.f, 0.f, 0.f, 0.f);

        for (int i = 0; i < myDeg; i += 2) {
            int s0 = sorted[myBeg + i];
            bool has1 = (i + 1 < myDeg);
            int s1 = has1 ? sorted[myBeg + i + 1] : s0;
            uint2 r0 = ((const uint2*)(y + (size_t)s0 * D))[q];
            uint2 r1 = ((const uint2*)(y + (size_t)s1 * D))[q];
            float2 a0 = __half22float2(*(const __half2*)&r0.x);
            float2 b0 = __half22float2(*(const __half2*)&r0.y);
            acc.x += a0.x; acc.y += a0.y; acc.z += b0.x; acc.w += b0.y;
            if (has1) {
                float2 a1 = __half22float2(*(const __half2*)&r1.x);
                float2 b1 = __half22float2(*(const __half2*)&r1.y);
                acc.x += a1.x; acc.y += a1.y; acc.z += b1.x; acc.w += b1.y;
            }
        }

        long g = (long)b * RB + n;
        if (g < N) {
            float4* op = (float4*)(out + g * D) + q;
            float4 z = *op;               // z staged by pre_kernel
            float4 r;
            r.x = tanhf(acc.x + z.x);
            r.y = tanhf(acc.y + z.y);
            r.z = tanhf(acc.z + z.z);
            r.w = tanhf(acc.w + z.w);
            *op = r;
        }
    }
}

extern "C" void kernel_launch(void* const* d_in, const int* in_sizes, int n_in,
                              void* d_out, int out_size, void* d_ws, size_t ws_size,
                              hipStream_t stream) {
    const float* x   = (const float*)d_in[0];
    const int* ei    = (const int*)d_in[1];   // [2,E] int32
    const float* W_l = (const float*)d_in[2];
    const float* b_l = (const float*)d_in[3];
    const float* W_r = (const float*)d_in[4];
    float* out = (float*)d_out;

    const int N = N_NODES;
    const int E = N_EDGES;
    const int* src = ei;
    const int* dst = ei + E;

    // workspace layout (total ~28.03 MB — under the proven 31.4 MB)
    char* ws = (char*)d_ws;
    ushort_t* y      = (ushort_t*)(ws);                  // 12,800,000 B
    unsigned* coarse = (unsigned*)(ws + 12800000);       // NCB*CCAP*4 = 5,619,712 B
    unsigned* fine   = (unsigned*)(ws + 18419712);       // NB*FCAP*4 = 9,603,072 B
    int* ccursor     = (int*)(ws + 28022784);            // 196 B (padded to 256)
    int* fcursor     = (int*)(ws + 28023040);            // 6,252 B

    pre_kernel<<<(N + TN - 1) / TN, 256, 0, stream>>>(
        x, W_l, b_l, W_r, y, out, ccursor, fcursor, N);
    partA_kernel<<<PARTA_BLOCKS, 256, 0, stream>>>(src, dst, ccursor, coarse, E);
    partB_kernel<<<NCB * SEGS, 256, 0, stream>>>(coarse, ccursor, fcursor, fine);
    sortgather_kernel<<<NB, 256, 0, stream>>>(y, fine, fcursor, out, N);
}

// Round 9
// 172.306 us; speedup vs baseline: 1.0575x; 1.0575x over previous
//
#include <hip/hip_runtime.h>
#include <hip/hip_bf16.h>
#include <hip/hip_fp16.h>

#define N_NODES 100000
#define D 64
#define N_EDGES 1250000

// fine buckets (sortgather granularity)
#define RB 64                   // nodes per fine bucket (dst>>6)
#define NB 1563                 // ceil(N / 64)
#define FCAP 1536               // fine slab capacity; mean 800, max ~950
#define SORT_CAP 1536

// coarse buckets (partition pass A)
#define CB_SHIFT 11             // 2048 nodes per coarse bucket
#define NCB 49                  // ceil(N / 2048)
#define CCAP 28672              // mean 25510, sigma ~158 -> +20 sigma
#define FINE_PER_COARSE 32      // 2048/64

#define EPB 8192                // edges per pass-A block
#define PARTA_BLOCKS ((N_EDGES + EPB - 1) / EPB)   // 153
#define SEGS 8                  // pass-B blocks per coarse bucket

typedef unsigned short ushort_t;

__device__ __forceinline__ ushort_t f2h(float f) {
    return __half_as_ushort(__float2half_rn(f));
}

// ---------------------------------------------------------------------------
// Pre-transform: y = fp16(x @ W_l) to ws; z = x @ W_r + b_l (fp32) into d_out
// (sortgather reads z back and overwrites with tanh(acc+z); each out element
// is owned by exactly one bucket block -> no race).
// Block 0 zeroes both cursor arrays (replaces memset dispatches).
// ---------------------------------------------------------------------------
#define TN 64
#define FS 68   // 64 + 4 pad

__global__ __launch_bounds__(256) void pre_kernel(
    const float* __restrict__ x, const float* __restrict__ W_l,
    const float* __restrict__ b_l, const float* __restrict__ W_r,
    ushort_t* __restrict__ y, float* __restrict__ zout,
    int* __restrict__ ccursor, int* __restrict__ fcursor, int N)
{
    __shared__ float sW[2 * 64 * 64];   // [0..4095]=W_l, [4096..8191]=W_r
    __shared__ float sX[TN * FS];

    int t = threadIdx.x;
    if (blockIdx.x == 0) {
        for (int i = t; i < NCB; i += 256) ccursor[i] = 0;
        for (int i = t; i < NB; i += 256) fcursor[i] = 0;
    }
    for (int i = t; i < 64 * 64; i += 256) {
        sW[i] = W_l[i];
        sW[4096 + i] = W_r[i];
    }

    long base = (long)blockIdx.x * TN;
    for (int i = t; i < TN * 16; i += 256) {   // 64 nodes x 16 float4
        int n = i >> 4, q = i & 15;
        long node = base + n;
        float4 v = make_float4(0.f, 0.f, 0.f, 0.f);
        if (node < N) v = ((const float4*)(x + node * D))[q];
        *(float4*)&sX[n * FS + q * 4] = v;
    }
    __syncthreads();

    const int og = (t & 15) * 4;
    const int ng = (t >> 4) * 4;
    float4 b = *(const float4*)(b_l + og);

    float accL[4][4], accR[4][4];
#pragma unroll
    for (int i = 0; i < 4; i++) {
        accL[i][0] = 0.f; accL[i][1] = 0.f; accL[i][2] = 0.f; accL[i][3] = 0.f;
        accR[i][0] = b.x; accR[i][1] = b.y; accR[i][2] = b.z; accR[i][3] = b.w;
    }

#pragma unroll 2
    for (int k = 0; k < 64; k += 4) {
        float4 wl[4], wr[4], a[4];
#pragma unroll
        for (int j = 0; j < 4; j++) {
            wl[j] = *(const float4*)&sW[(k + j) * 64 + og];
            wr[j] = *(const float4*)&sW[4096 + (k + j) * 64 + og];
        }
#pragma unroll
        for (int i = 0; i < 4; i++) a[i] = *(const float4*)&sX[(ng + i) * FS + k];
#pragma unroll
        for (int i = 0; i < 4; i++) {
            float av[4] = {a[i].x, a[i].y, a[i].z, a[i].w};
#pragma unroll
            for (int j = 0; j < 4; j++) {
                accL[i][0] += av[j] * wl[j].x;
                accL[i][1] += av[j] * wl[j].y;
                accL[i][2] += av[j] * wl[j].z;
                accL[i][3] += av[j] * wl[j].w;
                accR[i][0] += av[j] * wr[j].x;
                accR[i][1] += av[j] * wr[j].y;
                accR[i][2] += av[j] * wr[j].z;
                accR[i][3] += av[j] * wr[j].w;
            }
        }
    }

#pragma unroll
    for (int i = 0; i < 4; i++) {
        long node = base + ng + i;
        if (node < N) {
            ushort4 py;
            py.x = f2h(accL[i][0]); py.y = f2h(accL[i][1]);
            py.z = f2h(accL[i][2]); py.w = f2h(accL[i][3]);
            *(ushort4*)(y + node * D + og) = py;
            float4 pz = make_float4(accR[i][0], accR[i][1], accR[i][2], accR[i][3]);
            *(float4*)(zout + node * D + og) = pz;
        }
    }
}

// ---------------------------------------------------------------------------
// Partition pass A: 49 coarse buckets (dst>>11). Runs ~167 entries per
// (block,bucket) -> coalesced writes. Packs src | coarseLocal<<17.
// ---------------------------------------------------------------------------
__global__ __launch_bounds__(256) void partA_kernel(
    const int* __restrict__ src, const int* __restrict__ dst,
    int* __restrict__ ccursor, unsigned* __restrict__ coarse, int E)
{
    __shared__ int hist[NCB];
    __shared__ int bbase[NCB];
    int t = threadIdx.x;
    if (t < NCB) hist[t] = 0;
    __syncthreads();

    int base = blockIdx.x * EPB;
    int lim = E - base; if (lim > EPB) lim = EPB;

    for (int i = t; i < lim; i += 256) {
        int d = dst[base + i];
        atomicAdd(&hist[d >> CB_SHIFT], 1);
    }
    __syncthreads();

    if (t < NCB) {
        int c = hist[t];
        bbase[t] = c ? atomicAdd(&ccursor[t], c) : 0;
    }
    __syncthreads();

    for (int i = t; i < lim; i += 256) {
        int d = dst[base + i];
        int s = src[base + i];
        int b = d >> CB_SHIFT;
        int pos = atomicSub(&hist[b], 1) - 1;
        coarse[(size_t)b * CCAP + bbase[b] + pos] =
            (unsigned)s | ((unsigned)(d & ((1 << CB_SHIFT) - 1)) << 17);
    }
}

// ---------------------------------------------------------------------------
// Partition pass B: 8 segment-blocks per coarse bucket. Scatters into the 32
// fine buckets inside the coarse bucket (runs ~100 -> coalesced).
// Repacks src | fineLocal<<17.
// ---------------------------------------------------------------------------
__global__ __launch_bounds__(256) void partB_kernel(
    const unsigned* __restrict__ coarse, const int* __restrict__ ccursor,
    int* __restrict__ fcursor, unsigned* __restrict__ fine)
{
    __shared__ int hist[FINE_PER_COARSE];
    __shared__ int bbase[FINE_PER_COARSE];
    int cb = blockIdx.x >> 3;
    int seg = blockIdx.x & 7;
    int t = threadIdx.x;

    int cnt = ccursor[cb];
    int segLen = (cnt + SEGS - 1) / SEGS;
    int beg = seg * segLen;
    int end = beg + segLen; if (end > cnt) end = cnt;

    if (t < FINE_PER_COARSE) hist[t] = 0;
    __syncthreads();

    const unsigned* __restrict__ slab = coarse + (size_t)cb * CCAP;

    for (int i = beg + t; i < end; i += 256) {
        unsigned e = slab[i];
        atomicAdd(&hist[(e >> 17) >> 6], 1);
    }
    __syncthreads();

    if (t < FINE_PER_COARSE) {
        int c = hist[t];
        int fb = cb * FINE_PER_COARSE + t;
        bbase[t] = c ? atomicAdd(&fcursor[fb], c) : 0;
    }
    __syncthreads();

    for (int i = beg + t; i < end; i += 256) {
        unsigned e = slab[i];
        unsigned cl = e >> 17;
        int fb_loc = cl >> 6;
        int pos = atomicSub(&hist[fb_loc], 1) - 1;
        size_t fb = (size_t)cb * FINE_PER_COARSE + fb_loc;
        fine[fb * FCAP + bbase[fb_loc] + pos] =
            (e & 0x1FFFFu) | ((cl & 63u) << 17);
    }
}

// ---------------------------------------------------------------------------
// Fused sort + gather: one 512-thread block per fine bucket.
// Sort: slab entries staged in REGISTERS (<=3/thread), LDS int-atomic
//       counting sort over 64 local nodes.
// Gather: 8 lanes per node (64 groups = 64 nodes). Each lane loads uint4
//       (8 fp16 features): one wave-instr = 8 rows x 128 B = 1024 B (full
//       width). 4-edge unroll -> 4 independent loads in flight (the gather
//       is L2/HBM-latency-bound: round-7 showed 29% VALU, 29% HBM).
// Epilogue: out = tanh(acc + z), z staged in out by pre_kernel.
// ---------------------------------------------------------------------------
__global__ __launch_bounds__(512) void sortgather_kernel(
    const ushort_t* __restrict__ y, const unsigned* __restrict__ part,
    const int* __restrict__ cursor, float* __restrict__ out, int N)
{
    __shared__ int sorted[SORT_CAP];
    __shared__ int hist[RB];
    __shared__ int scanv[RB];
    __shared__ int cur[RB];
    __shared__ int begL[RB];

    int b = blockIdx.x;
    int t = threadIdx.x;
    int cnt = cursor[b];
    if (cnt > SORT_CAP) cnt = SORT_CAP;   // unreachable (max ~950)
    const unsigned* __restrict__ slab = part + (size_t)b * FCAP;

    // stage slab entries in registers (SORT_CAP = 3*512)
    unsigned e0 = 0, e1 = 0, e2 = 0;
    int i0 = t, i1 = t + 512, i2 = t + 1024;
    if (i0 < cnt) e0 = slab[i0];
    if (i1 < cnt) e1 = slab[i1];
    if (i2 < cnt) e2 = slab[i2];

    if (t < RB) hist[t] = 0;
    __syncthreads();

    if (i0 < cnt) atomicAdd(&hist[e0 >> 17], 1);
    if (i1 < cnt) atomicAdd(&hist[e1 >> 17], 1);
    if (i2 < cnt) atomicAdd(&hist[e2 >> 17], 1);
    __syncthreads();

    if (t < RB) scanv[t] = hist[t];
    __syncthreads();
#pragma unroll
    for (int off = 1; off < RB; off <<= 1) {
        int v = 0;
        if (t < RB && t >= off) v = scanv[t - off];
        __syncthreads();
        if (t < RB) scanv[t] += v;
        __syncthreads();
    }
    if (t < RB) {
        int ex = scanv[t] - hist[t];      // exclusive prefix
        cur[t] = ex;
        begL[t] = ex;
    }
    __syncthreads();

    if (i0 < cnt) { int p = atomicAdd(&cur[e0 >> 17], 1); sorted[p] = (int)(e0 & 0x1FFFF); }
    if (i1 < cnt) { int p = atomicAdd(&cur[e1 >> 17], 1); sorted[p] = (int)(e1 & 0x1FFFF); }
    if (i2 < cnt) { int p = atomicAdd(&cur[e2 >> 17], 1); sorted[p] = (int)(e2 & 0x1FFFF); }
    __syncthreads();

    // ---- gather phase: group g (8 lanes) owns node g ----
    const int g = t >> 3;     // local node 0..63
    const int f = t & 7;      // feature slice: halves 8f..8f+7
    int myBeg = begL[g];
    int myDeg = hist[g];

    float2 acc0 = make_float2(0.f, 0.f), acc1 = acc0, acc2 = acc0, acc3 = acc0;

    int i = 0;
    for (; i + 4 <= myDeg; i += 4) {
        int s0 = sorted[myBeg + i];
        int s1 = sorted[myBeg + i + 1];
        int s2 = sorted[myBeg + i + 2];
        int s3 = sorted[myBeg + i + 3];
        uint4 r0 = ((const uint4*)(y + (size_t)s0 * D))[f];
        uint4 r1 = ((const uint4*)(y + (size_t)s1 * D))[f];
        uint4 r2 = ((const uint4*)(y + (size_t)s2 * D))[f];
        uint4 r3 = ((const uint4*)(y + (size_t)s3 * D))[f];
#define ACC(r) { \
        float2 c0 = __half22float2(*(const __half2*)&(r).x); \
        float2 c1 = __half22float2(*(const __half2*)&(r).y); \
        float2 c2 = __half22float2(*(const __half2*)&(r).z); \
        float2 c3 = __half22float2(*(const __half2*)&(r).w); \
        acc0.x += c0.x; acc0.y += c0.y; acc1.x += c1.x; acc1.y += c1.y; \
        acc2.x += c2.x; acc2.y += c2.y; acc3.x += c3.x; acc3.y += c3.y; }
        ACC(r0) ACC(r1) ACC(r2) ACC(r3)
    }
    for (; i < myDeg; i++) {
        int s = sorted[myBeg + i];
        uint4 r = ((const uint4*)(y + (size_t)s * D))[f];
        ACC(r)
    }
#undef ACC

    long gn = (long)b * RB + g;
    if (gn < N) {
        float4* op = (float4*)(out + gn * D);
        float4 z0 = op[2 * f];
        float4 z1 = op[2 * f + 1];
        float4 o0, o1;
        o0.x = tanhf(acc0.x + z0.x); o0.y = tanhf(acc0.y + z0.y);
        o0.z = tanhf(acc1.x + z0.z); o0.w = tanhf(acc1.y + z0.w);
        o1.x = tanhf(acc2.x + z1.x); o1.y = tanhf(acc2.y + z1.y);
        o1.z = tanhf(acc3.x + z1.z); o1.w = tanhf(acc3.y + z1.w);
        op[2 * f] = o0;
        op[2 * f + 1] = o1;
    }
}

extern "C" void kernel_launch(void* const* d_in, const int* in_sizes, int n_in,
                              void* d_out, int out_size, void* d_ws, size_t ws_size,
                              hipStream_t stream) {
    const float* x   = (const float*)d_in[0];
    const int* ei    = (const int*)d_in[1];   // [2,E] int32
    const float* W_l = (const float*)d_in[2];
    const float* b_l = (const float*)d_in[3];
    const float* W_r = (const float*)d_in[4];
    float* out = (float*)d_out;

    const int N = N_NODES;
    const int E = N_EDGES;
    const int* src = ei;
    const int* dst = ei + E;

    // workspace layout (total ~28.03 MB — under the proven 31.4 MB)
    char* ws = (char*)d_ws;
    ushort_t* y      = (ushort_t*)(ws);                  // 12,800,000 B
    unsigned* coarse = (unsigned*)(ws + 12800000);       // NCB*CCAP*4 = 5,619,712 B
    unsigned* fine   = (unsigned*)(ws + 18419712);       // NB*FCAP*4 = 9,603,072 B
    int* ccursor     = (int*)(ws + 28022784);            // 196 B (padded to 256)
    int* fcursor     = (int*)(ws + 28023040);            // 6,252 B

    pre_kernel<<<(N + TN - 1) / TN, 256, 0, stream>>>(
        x, W_l, b_l, W_r, y, out, ccursor, fcursor, N);
    partA_kernel<<<PARTA_BLOCKS, 256, 0, stream>>>(src, dst, ccursor, coarse, E);
    partB_kernel<<<NCB * SEGS, 256, 0, stream>>>(coarse, ccursor, fcursor, fine);
    sortgather_kernel<<<NB, 512, 0, stream>>>(y, fine, fcursor, out, N);
}

// Round 10
// 151.056 us; speedup vs baseline: 1.2063x; 1.1407x over previous
//
#include <hip/hip_runtime.h>
#include <hip/hip_bf16.h>
#include <hip/hip_fp16.h>

#define N_NODES 100000
#define D 64
#define N_EDGES 1250000

// fine buckets (sortgather granularity)
#define RB 64                   // nodes per fine bucket (dst>>6)
#define NB 1563                 // ceil(N / 64)
#define FCAP 1536               // fine slab capacity; mean 800, max ~950
#define SORT_CAP 1536

// coarse buckets (partition pass A)
#define CB_SHIFT 11             // 2048 nodes per coarse bucket
#define NCB 49                  // ceil(N / 2048)
#define CCAP 28672              // mean 25510, sigma ~158 -> +20 sigma
#define FINE_PER_COARSE 32      // 2048/64

#define EPB 8192                // edges per pass-A block
#define PARTA_BLOCKS ((N_EDGES + EPB - 1) / EPB)   // 153
#define SEGS 8                  // pass-B blocks per coarse bucket

#define PRE_BLOCKS 1563         // ceil(N / 64)
#define FUSED_BLOCKS (PARTA_BLOCKS + PRE_BLOCKS)

typedef unsigned short ushort_t;

__device__ __forceinline__ ushort_t f2h(float f) {
    return __half_as_ushort(__float2half_rn(f));
}

// ---------------------------------------------------------------------------
// Fused pre-transform + partition pass A (data-independent -> one dispatch;
// partA's 153 blocks hide inside pre's ~20 us instead of serializing after).
//
// pre role  (blocks PARTA_BLOCKS..): y = fp16(x @ W_l), z = fp16(x @ W_r + b_l)
//   — aggregation commutes with the linear map: (sum x_j)@W_l = sum (x_j@W_l).
// partA role (blocks 0..PARTA_BLOCKS-1): scatter edges into 49 coarse buckets
//   (dst>>11); runs ~167 entries per (block,bucket) -> coalesced writes
//   (round-7 lesson: run length = EPB/NBUCKETS governs write amplification).
// Cursors are zeroed by a 6.5 KB hipMemsetAsync before this dispatch.
// ---------------------------------------------------------------------------
#define TN 64
#define FS 68   // 64 + 4 pad

__global__ __launch_bounds__(256) void pre_part_kernel(
    const float* __restrict__ x, const float* __restrict__ W_l,
    const float* __restrict__ b_l, const float* __restrict__ W_r,
    ushort_t* __restrict__ y, ushort_t* __restrict__ z,
    const int* __restrict__ src, const int* __restrict__ dst,
    int* __restrict__ ccursor, unsigned* __restrict__ coarse,
    int N, int E)
{
    int t = threadIdx.x;

    if (blockIdx.x < PARTA_BLOCKS) {
        // ---------------- partA role ----------------
        __shared__ int hist[NCB];
        __shared__ int bbase[NCB];
        if (t < NCB) hist[t] = 0;
        __syncthreads();

        int base = blockIdx.x * EPB;
        int lim = E - base; if (lim > EPB) lim = EPB;

        for (int i = t; i < lim; i += 256) {
            int d = dst[base + i];
            atomicAdd(&hist[d >> CB_SHIFT], 1);
        }
        __syncthreads();

        if (t < NCB) {
            int c = hist[t];
            bbase[t] = c ? atomicAdd(&ccursor[t], c) : 0;
        }
        __syncthreads();

        for (int i = t; i < lim; i += 256) {
            int d = dst[base + i];
            int s = src[base + i];
            int b = d >> CB_SHIFT;
            int pos = atomicSub(&hist[b], 1) - 1;
            coarse[(size_t)b * CCAP + bbase[b] + pos] =
                (unsigned)s | ((unsigned)(d & ((1 << CB_SHIFT) - 1)) << 17);
        }
        return;
    }

    // ---------------- pre role ----------------
    __shared__ float sW[2 * 64 * 64];   // [0..4095]=W_l, [4096..8191]=W_r
    __shared__ float sX[TN * FS];

    for (int i = t; i < 64 * 64; i += 256) {
        sW[i] = W_l[i];
        sW[4096 + i] = W_r[i];
    }

    long base = (long)(blockIdx.x - PARTA_BLOCKS) * TN;
    for (int i = t; i < TN * 16; i += 256) {   // 64 nodes x 16 float4
        int n = i >> 4, q = i & 15;
        long node = base + n;
        float4 v = make_float4(0.f, 0.f, 0.f, 0.f);
        if (node < N) v = ((const float4*)(x + node * D))[q];
        *(float4*)&sX[n * FS + q * 4] = v;
    }
    __syncthreads();

    const int og = (t & 15) * 4;
    const int ng = (t >> 4) * 4;
    float4 b = *(const float4*)(b_l + og);

    float accL[4][4], accR[4][4];
#pragma unroll
    for (int i = 0; i < 4; i++) {
        accL[i][0] = 0.f; accL[i][1] = 0.f; accL[i][2] = 0.f; accL[i][3] = 0.f;
        accR[i][0] = b.x; accR[i][1] = b.y; accR[i][2] = b.z; accR[i][3] = b.w;
    }

#pragma unroll 2
    for (int k = 0; k < 64; k += 4) {
        float4 wl[4], wr[4], a[4];
#pragma unroll
        for (int j = 0; j < 4; j++) {
            wl[j] = *(const float4*)&sW[(k + j) * 64 + og];
            wr[j] = *(const float4*)&sW[4096 + (k + j) * 64 + og];
        }
#pragma unroll
        for (int i = 0; i < 4; i++) a[i] = *(const float4*)&sX[(ng + i) * FS + k];
#pragma unroll
        for (int i = 0; i < 4; i++) {
            float av[4] = {a[i].x, a[i].y, a[i].z, a[i].w};
#pragma unroll
            for (int j = 0; j < 4; j++) {
                accL[i][0] += av[j] * wl[j].x;
                accL[i][1] += av[j] * wl[j].y;
                accL[i][2] += av[j] * wl[j].z;
                accL[i][3] += av[j] * wl[j].w;
                accR[i][0] += av[j] * wr[j].x;
                accR[i][1] += av[j] * wr[j].y;
                accR[i][2] += av[j] * wr[j].z;
                accR[i][3] += av[j] * wr[j].w;
            }
        }
    }

#pragma unroll
    for (int i = 0; i < 4; i++) {
        long node = base + ng + i;
        if (node < N) {
            ushort4 py, pz;
            py.x = f2h(accL[i][0]); py.y = f2h(accL[i][1]);
            py.z = f2h(accL[i][2]); py.w = f2h(accL[i][3]);
            pz.x = f2h(accR[i][0]); pz.y = f2h(accR[i][1]);
            pz.z = f2h(accR[i][2]); pz.w = f2h(accR[i][3]);
            *(ushort4*)(y + node * D + og) = py;
            *(ushort4*)(z + node * D + og) = pz;
        }
    }
}

// ---------------------------------------------------------------------------
// Partition pass B: 8 segment-blocks per coarse bucket. Scatters into the 32
// fine buckets inside the coarse bucket (runs ~100 -> coalesced).
// Repacks src | fineLocal<<17.
// ---------------------------------------------------------------------------
__global__ __launch_bounds__(256) void partB_kernel(
    const unsigned* __restrict__ coarse, const int* __restrict__ ccursor,
    int* __restrict__ fcursor, unsigned* __restrict__ fine)
{
    __shared__ int hist[FINE_PER_COARSE];
    __shared__ int bbase[FINE_PER_COARSE];
    int cb = blockIdx.x >> 3;
    int seg = blockIdx.x & 7;
    int t = threadIdx.x;

    int cnt = ccursor[cb];
    int segLen = (cnt + SEGS - 1) / SEGS;
    int beg = seg * segLen;
    int end = beg + segLen; if (end > cnt) end = cnt;

    if (t < FINE_PER_COARSE) hist[t] = 0;
    __syncthreads();

    const unsigned* __restrict__ slab = coarse + (size_t)cb * CCAP;

    for (int i = beg + t; i < end; i += 256) {
        unsigned e = slab[i];
        atomicAdd(&hist[(e >> 17) >> 6], 1);
    }
    __syncthreads();

    if (t < FINE_PER_COARSE) {
        int c = hist[t];
        int fb = cb * FINE_PER_COARSE + t;
        bbase[t] = c ? atomicAdd(&fcursor[fb], c) : 0;
    }
    __syncthreads();

    for (int i = beg + t; i < end; i += 256) {
        unsigned e = slab[i];
        unsigned cl = e >> 17;
        int fb_loc = cl >> 6;
        int pos = atomicSub(&hist[fb_loc], 1) - 1;
        size_t fb = (size_t)cb * FINE_PER_COARSE + fb_loc;
        fine[fb * FCAP + bbase[fb_loc] + pos] =
            (e & 0x1FFFFu) | ((cl & 63u) << 17);
    }
}

// ---------------------------------------------------------------------------
// Fused sort + gather: one 512-thread block per fine bucket.
// Sort: slab entries staged in registers (<=3/thread), LDS int-atomic
//       counting sort over 64 local nodes (round-5 lesson: int atomics only).
// Gather: 8 lanes per node; lane loads uint4 (8 fp16 feats) -> one wave-instr
//       = 8 rows x 128 B = 1024 B. 4-edge unroll for MLP (latency-bound).
// Epilogue: out = tanh(acc + z), z fp16 from ws (halves z traffic vs fp32).
// ---------------------------------------------------------------------------
__global__ __launch_bounds__(512) void sortgather_kernel(
    const ushort_t* __restrict__ y, const ushort_t* __restrict__ z,
    const unsigned* __restrict__ part, const int* __restrict__ cursor,
    float* __restrict__ out, int N)
{
    __shared__ int sorted[SORT_CAP];
    __shared__ int hist[RB];
    __shared__ int scanv[RB];
    __shared__ int cur[RB];
    __shared__ int begL[RB];

    int b = blockIdx.x;
    int t = threadIdx.x;
    int cnt = cursor[b];
    if (cnt > SORT_CAP) cnt = SORT_CAP;   // unreachable (max ~950)
    const unsigned* __restrict__ slab = part + (size_t)b * FCAP;

    // stage slab entries in registers (SORT_CAP = 3*512)
    unsigned e0 = 0, e1 = 0, e2 = 0;
    int i0 = t, i1 = t + 512, i2 = t + 1024;
    if (i0 < cnt) e0 = slab[i0];
    if (i1 < cnt) e1 = slab[i1];
    if (i2 < cnt) e2 = slab[i2];

    if (t < RB) hist[t] = 0;
    __syncthreads();

    if (i0 < cnt) atomicAdd(&hist[e0 >> 17], 1);
    if (i1 < cnt) atomicAdd(&hist[e1 >> 17], 1);
    if (i2 < cnt) atomicAdd(&hist[e2 >> 17], 1);
    __syncthreads();

    if (t < RB) scanv[t] = hist[t];
    __syncthreads();
#pragma unroll
    for (int off = 1; off < RB; off <<= 1) {
        int v = 0;
        if (t < RB && t >= off) v = scanv[t - off];
        __syncthreads();
        if (t < RB) scanv[t] += v;
        __syncthreads();
    }
    if (t < RB) {
        int ex = scanv[t] - hist[t];      // exclusive prefix
        cur[t] = ex;
        begL[t] = ex;
    }
    __syncthreads();

    if (i0 < cnt) { int p = atomicAdd(&cur[e0 >> 17], 1); sorted[p] = (int)(e0 & 0x1FFFF); }
    if (i1 < cnt) { int p = atomicAdd(&cur[e1 >> 17], 1); sorted[p] = (int)(e1 & 0x1FFFF); }
    if (i2 < cnt) { int p = atomicAdd(&cur[e2 >> 17], 1); sorted[p] = (int)(e2 & 0x1FFFF); }
    __syncthreads();

    // ---- gather phase: group g (8 lanes) owns node g ----
    const int g = t >> 3;     // local node 0..63
    const int f = t & 7;      // feature slice: halves 8f..8f+7
    int myBeg = begL[g];
    int myDeg = hist[g];

    float2 acc0 = make_float2(0.f, 0.f), acc1 = acc0, acc2 = acc0, acc3 = acc0;

    int i = 0;
    for (; i + 4 <= myDeg; i += 4) {
        int s0 = sorted[myBeg + i];
        int s1 = sorted[myBeg + i + 1];
        int s2 = sorted[myBeg + i + 2];
        int s3 = sorted[myBeg + i + 3];
        uint4 r0 = ((const uint4*)(y + (size_t)s0 * D))[f];
        uint4 r1 = ((const uint4*)(y + (size_t)s1 * D))[f];
        uint4 r2 = ((const uint4*)(y + (size_t)s2 * D))[f];
        uint4 r3 = ((const uint4*)(y + (size_t)s3 * D))[f];
#define ACC(r) { \
        float2 c0 = __half22float2(*(const __half2*)&(r).x); \
        float2 c1 = __half22float2(*(const __half2*)&(r).y); \
        float2 c2 = __half22float2(*(const __half2*)&(r).z); \
        float2 c3 = __half22float2(*(const __half2*)&(r).w); \
        acc0.x += c0.x; acc0.y += c0.y; acc1.x += c1.x; acc1.y += c1.y; \
        acc2.x += c2.x; acc2.y += c2.y; acc3.x += c3.x; acc3.y += c3.y; }
        ACC(r0) ACC(r1) ACC(r2) ACC(r3)
    }
    for (; i < myDeg; i++) {
        int s = sorted[myBeg + i];
        uint4 r = ((const uint4*)(y + (size_t)s * D))[f];
        ACC(r)
    }
#undef ACC

    long gn = (long)b * RB + g;
    if (gn < N) {
        uint4 zr = ((const uint4*)(z + (size_t)gn * D))[f];
        float2 z0 = __half22float2(*(const __half2*)&zr.x);
        float2 z1 = __half22float2(*(const __half2*)&zr.y);
        float2 z2 = __half22float2(*(const __half2*)&zr.z);
        float2 z3 = __half22float2(*(const __half2*)&zr.w);
        float4 o0, o1;
        o0.x = tanhf(acc0.x + z0.x); o0.y = tanhf(acc0.y + z0.y);
        o0.z = tanhf(acc1.x + z1.x); o0.w = tanhf(acc1.y + z1.y);
        o1.x = tanhf(acc2.x + z2.x); o1.y = tanhf(acc2.y + z2.y);
        o1.z = tanhf(acc3.x + z3.x); o1.w = tanhf(acc3.y + z3.y);
        float4* op = (float4*)(out + gn * D);
        op[2 * f] = o0;
        op[2 * f + 1] = o1;
    }
}

extern "C" void kernel_launch(void* const* d_in, const int* in_sizes, int n_in,
                              void* d_out, int out_size, void* d_ws, size_t ws_size,
                              hipStream_t stream) {
    const float* x   = (const float*)d_in[0];
    const int* ei    = (const int*)d_in[1];   // [2,E] int32
    const float* W_l = (const float*)d_in[2];
    const float* b_l = (const float*)d_in[3];
    const float* W_r = (const float*)d_in[4];
    float* out = (float*)d_out;

    const int N = N_NODES;
    const int E = N_EDGES;
    const int* src = ei;
    const int* dst = ei + E;

    // workspace layout (total ~40.8 MB; ws is 268 MB)
    char* ws = (char*)d_ws;
    ushort_t* y      = (ushort_t*)(ws);                  // 12,800,000 B
    ushort_t* z      = (ushort_t*)(ws + 12800000);       // 12,800,000 B
    unsigned* coarse = (unsigned*)(ws + 25600000);       // NCB*CCAP*4 = 5,619,712 B
    unsigned* fine   = (unsigned*)(ws + 31219712);       // NB*FCAP*4 = 9,603,072 B
    int* ccursor     = (int*)(ws + 40822784);            // 196 B (padded to 256)
    int* fcursor     = (int*)(ws + 40823040);            // NB*4 = 6,252 B

    // zero both cursor arrays (adjacent): 256 + 6252 bytes
    hipMemsetAsync(ccursor, 0, 6508, stream);

    pre_part_kernel<<<FUSED_BLOCKS, 256, 0, stream>>>(
        x, W_l, b_l, W_r, y, z, src, dst, ccursor, coarse, N, E);
    partB_kernel<<<NCB * SEGS, 256, 0, stream>>>(coarse, ccursor, fcursor, fine);
    sortgather_kernel<<<NB, 512, 0, stream>>>(y, z, fine, fcursor, out, N);
}

// Round 11
// 149.846 us; speedup vs baseline: 1.2161x; 1.0081x over previous
//
#include <hip/hip_runtime.h>
#include <hip/hip_bf16.h>
#include <hip/hip_fp16.h>

#define N_NODES 100000
#define D 64
#define N_EDGES 1250000

// fine buckets (sortgather granularity)
#define RB 64                   // nodes per fine bucket (dst>>6)
#define NB 1563                 // ceil(N / 64)
#define FCAP 1536               // fine slab capacity; mean 800, max ~950
#define SORT_CAP 1536

// coarse buckets (partition pass A)
#define CB_SHIFT 11             // 2048 nodes per coarse bucket
#define NCB 49                  // ceil(N / 2048)
#define CCAP 28672              // mean 25510, sigma ~158 -> +20 sigma
#define FINE_PER_COARSE 32      // 2048/64

#define EPB 8192                // edges per pass-A block
#define PARTA_BLOCKS ((N_EDGES + EPB - 1) / EPB)   // 153
#define SEGS 8                  // pass-B blocks per coarse bucket

#define TN 64                   // nodes per pre block
#define PRE_BLOCKS 1563         // ceil(N / 64)
#define FUSED_BLOCKS (PARTA_BLOCKS + PRE_BLOCKS)

#define XP 72                   // LDS fp16 row stride (64 + 8 pad -> 2-way-free b128)

typedef unsigned short ushort_t;
typedef _Float16 half_t;
typedef __attribute__((ext_vector_type(8))) _Float16 half8;
typedef __attribute__((ext_vector_type(4))) float floatx4;

// ---------------------------------------------------------------------------
// Fused pre-transform + partition pass A (one dispatch; partA's 153 blocks
// hide inside pre).
//
// pre role (blocks PARTA_BLOCKS..): [Y|Z] = X @ [W_l|W_r] via fp16 MFMA
//   (mfma_f32_16x16x32_f16, fp32 accumulate). Aggregation commutes with the
//   linear map: (sum x_j)@W_l = sum (x_j@W_l). Round-10 showed the fp32 VALU
//   version ran at 32% issue for ~35 us; MFMA makes pre memory-bound.
//   Fragment maps: A[m=lane&15][k=quad*8+j], B[k=quad*8+j][n=lane&15],
//   C/D col=lane&15 row=quad*4+reg (dtype-independent).
// partA role (blocks 0..PARTA_BLOCKS-1): scatter edges into 49 coarse
//   buckets (dst>>11); runs ~167 entries -> coalesced writes.
// Cursors zeroed by a 6.5 KB hipMemsetAsync before this dispatch.
// ---------------------------------------------------------------------------
__global__ __launch_bounds__(256) void pre_part_kernel(
    const float* __restrict__ x, const float* __restrict__ W_l,
    const float* __restrict__ b_l, const float* __restrict__ W_r,
    ushort_t* __restrict__ y, ushort_t* __restrict__ z,
    const int* __restrict__ src, const int* __restrict__ dst,
    int* __restrict__ ccursor, unsigned* __restrict__ coarse,
    int N, int E)
{
    int t = threadIdx.x;

    if (blockIdx.x < PARTA_BLOCKS) {
        // ---------------- partA role ----------------
        __shared__ int hist[NCB];
        __shared__ int bbase[NCB];
        if (t < NCB) hist[t] = 0;
        __syncthreads();

        int base = blockIdx.x * EPB;
        int lim = E - base; if (lim > EPB) lim = EPB;

        for (int i = t; i < lim; i += 256) {
            int d = dst[base + i];
            atomicAdd(&hist[d >> CB_SHIFT], 1);
        }
        __syncthreads();

        if (t < NCB) {
            int c = hist[t];
            bbase[t] = c ? atomicAdd(&ccursor[t], c) : 0;
        }
        __syncthreads();

        for (int i = t; i < lim; i += 256) {
            int d = dst[base + i];
            int s = src[base + i];
            int b = d >> CB_SHIFT;
            int pos = atomicSub(&hist[b], 1) - 1;
            coarse[(size_t)b * CCAP + bbase[b] + pos] =
                (unsigned)s | ((unsigned)(d & ((1 << CB_SHIFT) - 1)) << 17);
        }
        return;
    }

    // ---------------- pre role (MFMA) ----------------
    __shared__ half_t sWt[128 * XP];   // sWt[col][k] = W[k][col], 18,432 B
    __shared__ half_t sXh[TN * XP];    // sXh[node][k] fp16,        9,216 B

    // stage W transposed fp16 (W_l -> cols 0..63, W_r -> cols 64..127)
    for (int i = t; i < 64 * 64; i += 256) {
        int k = i >> 6, c = i & 63;
        sWt[c * XP + k]        = (half_t)W_l[i];
        sWt[(64 + c) * XP + k] = (half_t)W_r[i];
    }

    long base = (long)(blockIdx.x - PARTA_BLOCKS) * TN;
    for (int i = t; i < TN * 16; i += 256) {   // 64 nodes x 16 float4
        int n = i >> 4, q = i & 15;
        long node = base + n;
        float4 v = make_float4(0.f, 0.f, 0.f, 0.f);
        if (node < N) v = ((const float4*)(x + node * D))[q];
        half_t* p = &sXh[n * XP + q * 4];
        p[0] = (half_t)v.x; p[1] = (half_t)v.y;
        p[2] = (half_t)v.z; p[3] = (half_t)v.w;
    }
    __syncthreads();

    const int lane  = t & 63;
    const int w     = t >> 6;        // wave id = node-tile 0..3
    const int col16 = lane & 15;
    const int quad  = lane >> 4;

    // A fragments (this wave's 16 nodes), k-chunks 0..31 / 32..63
    const int nrow = w * 16 + col16;             // m = lane&15
    half8 a0 = *(half8*)&sXh[nrow * XP + quad * 8];
    half8 a1 = *(half8*)&sXh[nrow * XP + 32 + quad * 8];

    float bias[4];
#pragma unroll
    for (int j = 0; j < 4; j++) bias[j] = b_l[j * 16 + col16];

    long nodeBase = base + w * 16;

#pragma unroll 2
    for (int ct = 0; ct < 8; ct++) {
        int c = ct * 16 + col16;                 // n = lane&15
        half8 b0 = *(half8*)&sWt[c * XP + quad * 8];
        half8 b1 = *(half8*)&sWt[c * XP + 32 + quad * 8];
        floatx4 acc = {0.f, 0.f, 0.f, 0.f};
        acc = __builtin_amdgcn_mfma_f32_16x16x32_f16(a0, b0, acc, 0, 0, 0);
        acc = __builtin_amdgcn_mfma_f32_16x16x32_f16(a1, b1, acc, 0, 0, 0);

        ushort_t* obuf = (ct < 4) ? y : z;
        int cc    = (ct < 4) ? c : (c - 64);
        float badd = (ct < 4) ? 0.f : bias[ct - 4];
#pragma unroll
        for (int r = 0; r < 4; r++) {
            long node = nodeBase + quad * 4 + r;   // row = quad*4 + reg
            if (node < N) {
                half_t hv = (half_t)(acc[r] + badd);
                obuf[node * D + cc] = *(ushort_t*)&hv;
            }
        }
    }
}

// ---------------------------------------------------------------------------
// Partition pass B: 8 segment-blocks per coarse bucket. Scatters into the 32
// fine buckets inside the coarse bucket (runs ~100 -> coalesced).
// Repacks src | fineLocal<<17.
// ---------------------------------------------------------------------------
__global__ __launch_bounds__(256) void partB_kernel(
    const unsigned* __restrict__ coarse, const int* __restrict__ ccursor,
    int* __restrict__ fcursor, unsigned* __restrict__ fine)
{
    __shared__ int hist[FINE_PER_COARSE];
    __shared__ int bbase[FINE_PER_COARSE];
    int cb = blockIdx.x >> 3;
    int seg = blockIdx.x & 7;
    int t = threadIdx.x;

    int cnt = ccursor[cb];
    int segLen = (cnt + SEGS - 1) / SEGS;
    int beg = seg * segLen;
    int end = beg + segLen; if (end > cnt) end = cnt;

    if (t < FINE_PER_COARSE) hist[t] = 0;
    __syncthreads();

    const unsigned* __restrict__ slab = coarse + (size_t)cb * CCAP;

    for (int i = beg + t; i < end; i += 256) {
        unsigned e = slab[i];
        atomicAdd(&hist[(e >> 17) >> 6], 1);
    }
    __syncthreads();

    if (t < FINE_PER_COARSE) {
        int c = hist[t];
        int fb = cb * FINE_PER_COARSE + t;
        bbase[t] = c ? atomicAdd(&fcursor[fb], c) : 0;
    }
    __syncthreads();

    for (int i = beg + t; i < end; i += 256) {
        unsigned e = slab[i];
        unsigned cl = e >> 17;
        int fb_loc = cl >> 6;
        int pos = atomicSub(&hist[fb_loc], 1) - 1;
        size_t fb = (size_t)cb * FINE_PER_COARSE + fb_loc;
        fine[fb * FCAP + bbase[fb_loc] + pos] =
            (e & 0x1FFFFu) | ((cl & 63u) << 17);
    }
}

// ---------------------------------------------------------------------------
// Fused sort + gather: one 512-thread block per fine bucket.
// Sort: slab entries staged in registers (<=3/thread), LDS int-atomic
//       counting sort over 64 local nodes (round-5 lesson: int atomics only).
// Gather: 8 lanes per node; lane loads uint4 (8 fp16 feats) -> one wave-instr
//       = 8 rows x 128 B = 1024 B. 4-edge unroll for MLP (latency-bound).
// Epilogue: out = tanh(acc + z), z fp16 from ws.
// ---------------------------------------------------------------------------
__global__ __launch_bounds__(512) void sortgather_kernel(
    const ushort_t* __restrict__ y, const ushort_t* __restrict__ z,
    const unsigned* __restrict__ part, const int* __restrict__ cursor,
    float* __restrict__ out, int N)
{
    __shared__ int sorted[SORT_CAP];
    __shared__ int hist[RB];
    __shared__ int scanv[RB];
    __shared__ int cur[RB];
    __shared__ int begL[RB];

    int b = blockIdx.x;
    int t = threadIdx.x;
    int cnt = cursor[b];
    if (cnt > SORT_CAP) cnt = SORT_CAP;   // unreachable (max ~950)
    const unsigned* __restrict__ slab = part + (size_t)b * FCAP;

    // stage slab entries in registers (SORT_CAP = 3*512)
    unsigned e0 = 0, e1 = 0, e2 = 0;
    int i0 = t, i1 = t + 512, i2 = t + 1024;
    if (i0 < cnt) e0 = slab[i0];
    if (i1 < cnt) e1 = slab[i1];
    if (i2 < cnt) e2 = slab[i2];

    if (t < RB) hist[t] = 0;
    __syncthreads();

    if (i0 < cnt) atomicAdd(&hist[e0 >> 17], 1);
    if (i1 < cnt) atomicAdd(&hist[e1 >> 17], 1);
    if (i2 < cnt) atomicAdd(&hist[e2 >> 17], 1);
    __syncthreads();

    if (t < RB) scanv[t] = hist[t];
    __syncthreads();
#pragma unroll
    for (int off = 1; off < RB; off <<= 1) {
        int v = 0;
        if (t < RB && t >= off) v = scanv[t - off];
        __syncthreads();
        if (t < RB) scanv[t] += v;
        __syncthreads();
    }
    if (t < RB) {
        int ex = scanv[t] - hist[t];      // exclusive prefix
        cur[t] = ex;
        begL[t] = ex;
    }
    __syncthreads();

    if (i0 < cnt) { int p = atomicAdd(&cur[e0 >> 17], 1); sorted[p] = (int)(e0 & 0x1FFFF); }
    if (i1 < cnt) { int p = atomicAdd(&cur[e1 >> 17], 1); sorted[p] = (int)(e1 & 0x1FFFF); }
    if (i2 < cnt) { int p = atomicAdd(&cur[e2 >> 17], 1); sorted[p] = (int)(e2 & 0x1FFFF); }
    __syncthreads();

    // ---- gather phase: group g (8 lanes) owns node g ----
    const int g = t >> 3;     // local node 0..63
    const int f = t & 7;      // feature slice: halves 8f..8f+7
    int myBeg = begL[g];
    int myDeg = hist[g];

    float2 acc0 = make_float2(0.f, 0.f), acc1 = acc0, acc2 = acc0, acc3 = acc0;

    int i = 0;
    for (; i + 4 <= myDeg; i += 4) {
        int s0 = sorted[myBeg + i];
        int s1 = sorted[myBeg + i + 1];
        int s2 = sorted[myBeg + i + 2];
        int s3 = sorted[myBeg + i + 3];
        uint4 r0 = ((const uint4*)(y + (size_t)s0 * D))[f];
        uint4 r1 = ((const uint4*)(y + (size_t)s1 * D))[f];
        uint4 r2 = ((const uint4*)(y + (size_t)s2 * D))[f];
        uint4 r3 = ((const uint4*)(y + (size_t)s3 * D))[f];
#define ACC(r) { \
        float2 c0 = __half22float2(*(const __half2*)&(r).x); \
        float2 c1 = __half22float2(*(const __half2*)&(r).y); \
        float2 c2 = __half22float2(*(const __half2*)&(r).z); \
        float2 c3 = __half22float2(*(const __half2*)&(r).w); \
        acc0.x += c0.x; acc0.y += c0.y; acc1.x += c1.x; acc1.y += c1.y; \
        acc2.x += c2.x; acc2.y += c2.y; acc3.x += c3.x; acc3.y += c3.y; }
        ACC(r0) ACC(r1) ACC(r2) ACC(r3)
    }
    for (; i < myDeg; i++) {
        int s = sorted[myBeg + i];
        uint4 r = ((const uint4*)(y + (size_t)s * D))[f];
        ACC(r)
    }
#undef ACC

    long gn = (long)b * RB + g;
    if (gn < N) {
        uint4 zr = ((const uint4*)(z + (size_t)gn * D))[f];
        float2 z0 = __half22float2(*(const __half2*)&zr.x);
        float2 z1 = __half22float2(*(const __half2*)&zr.y);
        float2 z2 = __half22float2(*(const __half2*)&zr.z);
        float2 z3 = __half22float2(*(const __half2*)&zr.w);
        float4 o0, o1;
        o0.x = tanhf(acc0.x + z0.x); o0.y = tanhf(acc0.y + z0.y);
        o0.z = tanhf(acc1.x + z1.x); o0.w = tanhf(acc1.y + z1.y);
        o1.x = tanhf(acc2.x + z2.x); o1.y = tanhf(acc2.y + z2.y);
        o1.z = tanhf(acc3.x + z3.x); o1.w = tanhf(acc3.y + z3.y);
        float4* op = (float4*)(out + gn * D);
        op[2 * f] = o0;
        op[2 * f + 1] = o1;
    }
}

extern "C" void kernel_launch(void* const* d_in, const int* in_sizes, int n_in,
                              void* d_out, int out_size, void* d_ws, size_t ws_size,
                              hipStream_t stream) {
    const float* x   = (const float*)d_in[0];
    const int* ei    = (const int*)d_in[1];   // [2,E] int32
    const float* W_l = (const float*)d_in[2];
    const float* b_l = (const float*)d_in[3];
    const float* W_r = (const float*)d_in[4];
    float* out = (float*)d_out;

    const int N = N_NODES;
    const int E = N_EDGES;
    const int* src = ei;
    const int* dst = ei + E;

    // workspace layout (total ~40.8 MB; ws is 268 MB)
    char* ws = (char*)d_ws;
    ushort_t* y      = (ushort_t*)(ws);                  // 12,800,000 B
    ushort_t* z      = (ushort_t*)(ws + 12800000);       // 12,800,000 B
    unsigned* coarse = (unsigned*)(ws + 25600000);       // NCB*CCAP*4 = 5,619,712 B
    unsigned* fine   = (unsigned*)(ws + 31219712);       // NB*FCAP*4 = 9,603,072 B
    int* ccursor     = (int*)(ws + 40822784);            // 196 B (padded to 256)
    int* fcursor     = (int*)(ws + 40823040);            // NB*4 = 6,252 B

    // zero both cursor arrays (adjacent): 256 + 6252 bytes
    hipMemsetAsync(ccursor, 0, 6508, stream);

    pre_part_kernel<<<FUSED_BLOCKS, 256, 0, stream>>>(
        x, W_l, b_l, W_r, y, z, src, dst, ccursor, coarse, N, E);
    partB_kernel<<<NCB * SEGS, 256, 0, stream>>>(coarse, ccursor, fcursor, fine);
    sortgather_kernel<<<NB, 512, 0, stream>>>(y, z, fine, fcursor, out, N);
}